// Round 1
// baseline (155.497 us; speedup 1.0000x reference)
//
#include <hip/hip_runtime.h>
#include <cmath>

// B-matrix for the Pauli decomposition of psi psi^T per wire:
// B0 = I/2, B1 = Z/2, B2 = X/2
__device__ __forceinline__ float Bv(int i, int a, int b) {
  if (i == 0) return (a == b) ? 0.5f : 0.0f;
  if (i == 1) return (a == b) ? (a ? -0.5f : 0.5f) : 0.0f;
  return (a != b) ? 0.5f : 0.0f;
}

// Prep: from qweights [3][4][2] compute the 16x16 circuit unitary U,
// M_w = Re(U^dag Z_w U), then the factorized coefficient tensor
// A[p][q][w] (p = i0*3+i1, q = i2*3+i3, basis per wire {I/2, Z/2, X/2}).
__global__ __launch_bounds__(256) void qprep_kernel(
    const float* __restrict__ qw,   // [3][4][2]
    float* __restrict__ A_out)      // [81][4] floats
{
  __shared__ float Ure[16][16];   // [u][col]
  __shared__ float Uim[16][16];
  __shared__ float M[4][16][16];
  const int tid = threadIdx.x;

  if (tid < 16) {
    // simulate column |tid> through 3 layers; wire 0 = MSB (mask 8>>w)
    float sr[16], si[16];
#pragma unroll
    for (int u = 0; u < 16; ++u) { sr[u] = (u == tid) ? 1.0f : 0.0f; si[u] = 0.0f; }

#pragma unroll
    for (int l = 0; l < 3; ++l) {
#pragma unroll
      for (int w = 0; w < 4; ++w) {
        const int mask = 8 >> w;
        // RY(qw[l][w][0])
        float th = qw[(l * 4 + w) * 2 + 0];
        float sh, ch;
        __sincosf(0.5f * th, &sh, &ch);
#pragma unroll
        for (int u = 0; u < 16; ++u) {
          if (u & mask) continue;
          const int v = u | mask;
          const float ar = sr[u], ai = si[u], br = sr[v], bi = si[v];
          sr[u] = ch * ar - sh * br; si[u] = ch * ai - sh * bi;
          sr[v] = sh * ar + ch * br; si[v] = sh * ai + ch * bi;
        }
        // RZ(qw[l][w][1]): bit0 -> *(c - i s), bit1 -> *(c + i s)
        th = qw[(l * 4 + w) * 2 + 1];
        __sincosf(0.5f * th, &sh, &ch);
#pragma unroll
        for (int u = 0; u < 16; ++u) {
          const float r = sr[u], m2 = si[u];
          if (u & mask) { sr[u] = ch * r - sh * m2; si[u] = ch * m2 + sh * r; }
          else          { sr[u] = ch * r + sh * m2; si[u] = ch * m2 - sh * r; }
        }
      }
      // CNOT ring: (0,1),(1,2),(2,3),(3,0) in order
#pragma unroll
      for (int w = 0; w < 4; ++w) {
        const int cm = 8 >> w;
        const int tm = 8 >> ((w + 1) & 3);
#pragma unroll
        for (int u = 0; u < 16; ++u) {
          if ((u & cm) && !(u & tm)) {
            const int v = u | tm;
            float t = sr[u]; sr[u] = sr[v]; sr[v] = t;
            t = si[u]; si[u] = si[v]; si[v] = t;
          }
        }
      }
    }
#pragma unroll
    for (int u = 0; u < 16; ++u) { Ure[u][tid] = sr[u]; Uim[u][tid] = si[u]; }
  }
  __syncthreads();

  // M[w][s][t] = sum_u z_w(u) * Re(conj(U[u,s]) U[u,t])
  for (int idx = tid; idx < 1024; idx += 256) {
    const int w = idx >> 8, s = (idx >> 4) & 15, t = idx & 15;
    const int mask = 8 >> w;
    float acc = 0.0f;
    for (int u = 0; u < 16; ++u) {
      const float z = (u & mask) ? -1.0f : 1.0f;
      acc += z * (Ure[u][s] * Ure[u][t] + Uim[u][s] * Uim[u][t]);
    }
    M[w][s][t] = acc;
  }
  __syncthreads();

  // A[pq][w] = sum_{s,t} M[w][s][t] * prod_k B_{i_k}[s_k, t_k]
  for (int idx = tid; idx < 324; idx += 256) {
    const int w = idx & 3;
    const int pq = idx >> 2;
    const int p = pq / 9, q = pq % 9;
    const int i0 = p / 3, i1 = p % 3, i2 = q / 3, i3 = q % 3;
    float acc = 0.0f;
    for (int s = 0; s < 16; ++s)
      for (int t = 0; t < 16; ++t) {
        const float bprod = Bv(i0, (s >> 3) & 1, (t >> 3) & 1) *
                            Bv(i1, (s >> 2) & 1, (t >> 2) & 1) *
                            Bv(i2, (s >> 1) & 1, (t >> 1) & 1) *
                            Bv(i3, s & 1, t & 1);
        acc = fmaf(M[w][s][t], bprod, acc);
      }
    A_out[idx] = acc;   // layout [pq*4 + w]
  }
}

// Main: per batch element, GEMV(64->4) + tanh + sincos + 9x9x4 contraction.
__global__ __launch_bounds__(256) void qmain_kernel(
    const float* __restrict__ x,    // [B][64]
    const float* __restrict__ Wp,   // [4][64]
    const float* __restrict__ bp,   // [4]
    const float* __restrict__ A,    // [81][4]
    float* __restrict__ out)        // [B][4]
{
  __shared__ float xt[256 * 17];    // 256 rows x 16 feats, pad stride 17
  const int tid = threadIdx.x;
  const size_t row0 = (size_t)blockIdx.x * 256;

  float a0 = 0.f, a1 = 0.f, a2 = 0.f, a3 = 0.f;
#pragma unroll
  for (int c = 0; c < 4; ++c) {
    // stage features [16c, 16c+16) for rows [row0, row0+256) -- coalesced
    // 64B-granule loads: lanes 4r..4r+3 cover one row's 64B chunk.
#pragma unroll
    for (int p = 0; p < 4; ++p) {
      const int row = p * 64 + (tid >> 2);
      const int q4 = (tid & 3) << 2;
      const float4 v = *reinterpret_cast<const float4*>(
          x + (row0 + (size_t)row) * 64 + c * 16 + q4);
      float* d = &xt[row * 17 + q4];
      d[0] = v.x; d[1] = v.y; d[2] = v.z; d[3] = v.w;
    }
    __syncthreads();
#pragma unroll
    for (int f = 0; f < 16; ++f) {
      const float xv = xt[tid * 17 + f];   // stride 17: conflict-free
      const int fg = c * 16 + f;
      a0 = fmaf(xv, Wp[fg], a0);           // W reads wave-uniform -> s_load
      a1 = fmaf(xv, Wp[64 + fg], a1);
      a2 = fmaf(xv, Wp[128 + fg], a2);
      a3 = fmaf(xv, Wp[192 + fg], a3);
    }
    __syncthreads();
  }

  const float t0 = tanhf(a0 + bp[0]);
  const float t1 = tanhf(a1 + bp[1]);
  const float t2 = tanhf(a2 + bp[2]);
  const float t3 = tanhf(a3 + bp[3]);

  float c0, s0, c1, s1, c2, s2, c3, s3;
  __sincosf(t0, &s0, &c0);
  __sincosf(t1, &s1, &c1);
  __sincosf(t2, &s2, &c2);
  __sincosf(t3, &s3, &c3);

  // g[p] = f0[i0]*f1[i1], h[q] = f2[i2]*f3[i3], f = (1, cos, sin)
  const float g[9] = {1.f, c1, s1, c0, c0 * c1, c0 * s1, s0, s0 * c1, s0 * s1};
  const float h[9] = {1.f, c3, s3, c2, c2 * c3, c2 * s3, s2, s2 * c3, s2 * s3};

  float e0 = 0.f, e1 = 0.f, e2 = 0.f, e3 = 0.f;
#pragma unroll
  for (int p = 0; p < 9; ++p) {
#pragma unroll
    for (int q = 0; q < 9; ++q) {
      const float t = g[p] * h[q];
      const float* a4 = &A[(p * 9 + q) * 4];   // uniform -> s_load
      e0 = fmaf(a4[0], t, e0);
      e1 = fmaf(a4[1], t, e1);
      e2 = fmaf(a4[2], t, e2);
      e3 = fmaf(a4[3], t, e3);
    }
  }
  reinterpret_cast<float4*>(out)[row0 + tid] = make_float4(e0, e1, e2, e3);
}

extern "C" void kernel_launch(void* const* d_in, const int* in_sizes, int n_in,
                              void* d_out, int out_size, void* d_ws, size_t ws_size,
                              hipStream_t stream) {
  const float* x  = (const float*)d_in[0];
  const float* Wp = (const float*)d_in[1];
  const float* bp = (const float*)d_in[2];
  const float* qw = (const float*)d_in[3];
  float* out = (float*)d_out;
  float* A = (float*)d_ws;   // 324 floats

  qprep_kernel<<<1, 256, 0, stream>>>(qw, A);

  const int B = in_sizes[0] / 64;        // 524288
  qmain_kernel<<<B / 256, 256, 0, stream>>>(x, Wp, bp, A, out);
}

// Round 2
// 42.591 us; speedup vs baseline: 3.6509x; 3.6509x over previous
//
#include <hip/hip_runtime.h>
#include <cmath>

// Prep: from qweights [3][4][2] compute the 16x16 circuit unitary U
// (3 layers of fixed RY/RZ + CNOT ring), M_w = Re(U^dag Z_w U), then the
// factorized coefficient tensor A[p][q][w] (p = i0*3+i1, q = i2*3+i3,
// per-wire basis {I/2, Z/2, X/2}).
//
// Parallelization: 256 threads = 16 columns x 16 amplitudes; each thread
// owns ONE complex amplitude in LDS (no per-thread arrays -> no scratch).
__global__ __launch_bounds__(256) void qprep_kernel(
    const float* __restrict__ qw,   // [3][4][2]
    float* __restrict__ A_out)      // [81][4] floats
{
  __shared__ float sre[16][17];   // [col][u], pad -> conflict-free
  __shared__ float sim[16][17];
  __shared__ float M[4][16][16];
  const int tid = threadIdx.x;
  const int col = tid >> 4;
  const int u   = tid & 15;

  sre[col][u] = (u == col) ? 1.0f : 0.0f;
  sim[col][u] = 0.0f;
  __syncthreads();

#pragma unroll
  for (int l = 0; l < 3; ++l) {
#pragma unroll
    for (int w = 0; w < 4; ++w) {
      const int mask = 8 >> w;     // wire 0 = MSB
      float sh, ch, sh2, ch2;
      __sincosf(0.5f * qw[(l * 4 + w) * 2 + 0], &sh, &ch);    // RY
      __sincosf(0.5f * qw[(l * 4 + w) * 2 + 1], &sh2, &ch2);  // RZ
      // RY butterfly partners
      const int ua = u & ~mask, ub = u | mask;
      const float ar = sre[col][ua], ai = sim[col][ua];
      const float br = sre[col][ub], bi = sim[col][ub];
      __syncthreads();
      float nr, ni;
      if (u & mask) { nr = sh * ar + ch * br; ni = sh * ai + ch * bi; }
      else          { nr = ch * ar - sh * br; ni = ch * ai - sh * bi; }
      // RZ phase: bit set -> *(ch2 + i sh2), clear -> *(ch2 - i sh2)
      float rr, ri;
      if (u & mask) { rr = ch2 * nr - sh2 * ni; ri = ch2 * ni + sh2 * nr; }
      else          { rr = ch2 * nr + sh2 * ni; ri = ch2 * ni - sh2 * nr; }
      sre[col][u] = rr; sim[col][u] = ri;
      __syncthreads();
    }
    // CNOT ring (0,1)(1,2)(2,3)(3,0) composed into ONE permutation:
    // state'[u] = state[src], src = sigma0(sigma1(sigma2(sigma3(u))))
    int src = u;
    if (src & 1) src ^= 8;   // CNOT(3,0): ctrl bit0, tgt bit3
    if (src & 2) src ^= 1;   // CNOT(2,3)
    if (src & 4) src ^= 2;   // CNOT(1,2)
    if (src & 8) src ^= 4;   // CNOT(0,1)
    const float pr = sre[col][src], pi = sim[col][src];
    __syncthreads();
    sre[col][u] = pr; sim[col][u] = pi;
    __syncthreads();
  }

  // Now sre[col][u] = U[u][col].
  // M[w][s][t] = sum_u z_w(u) * Re(conj(U[u,s]) U[u,t])
  for (int idx = tid; idx < 1024; idx += 256) {
    const int w = idx >> 8, s = (idx >> 4) & 15, t = idx & 15;
    const int mask = 8 >> w;
    float acc = 0.0f;
#pragma unroll
    for (int uu = 0; uu < 16; ++uu) {
      const float z = (uu & mask) ? -1.0f : 1.0f;
      acc += z * (sre[s][uu] * sre[t][uu] + sim[s][uu] * sim[t][uu]);
    }
    M[w][s][t] = acc;
  }
  __syncthreads();

  // A[pq][w] = sum_{s,t} M[w][s][t] * prod_k B_{i_k}[s_k, t_k]
  // Each per-wire B_i has exactly 2 nonzeros -> 16-term sparse sum:
  //   i=0 (I/2): (j,j, +.5)   i=1 (Z/2): (j,j, j? -.5:+.5)   i=2 (X/2): (j,1-j, +.5)
  for (int idx = tid; idx < 324; idx += 256) {
    const int w = idx & 3, pq = idx >> 2;
    const int p = pq / 9, q = pq % 9;
    const int i0 = p / 3, i1 = p % 3, i2 = q / 3, i3 = q % 3;
    float acc = 0.0f;
#pragma unroll
    for (int comb = 0; comb < 16; ++comb) {
      int s = 0, t = 0;
      float coef = 0.0625f;   // 0.5^4
      int j;
      j = (comb >> 3) & 1; s |= j << 3; t |= ((i0 == 2) ? (j ^ 1) : j) << 3; if (i0 == 1 && j) coef = -coef;
      j = (comb >> 2) & 1; s |= j << 2; t |= ((i1 == 2) ? (j ^ 1) : j) << 2; if (i1 == 1 && j) coef = -coef;
      j = (comb >> 1) & 1; s |= j << 1; t |= ((i2 == 2) ? (j ^ 1) : j) << 1; if (i2 == 1 && j) coef = -coef;
      j = comb & 1;        s |= j;      t |= ((i3 == 2) ? (j ^ 1) : j);      if (i3 == 1 && j) coef = -coef;
      acc = fmaf(coef, M[w][s][t], acc);
    }
    A_out[idx] = acc;   // layout [pq*4 + w]
  }
}

// Main: per batch element, GEMV(64->4) + tanh + sincos + 9x9x4 contraction.
__global__ __launch_bounds__(256) void qmain_kernel(
    const float* __restrict__ x,    // [B][64]
    const float* __restrict__ Wp,   // [4][64]
    const float* __restrict__ bp,   // [4]
    const float* __restrict__ A,    // [81][4]
    float* __restrict__ out)        // [B][4]
{
  __shared__ float xt[256 * 17];    // 256 rows x 16 feats, pad stride 17
  const int tid = threadIdx.x;
  const size_t row0 = (size_t)blockIdx.x * 256;

  float a0 = 0.f, a1 = 0.f, a2 = 0.f, a3 = 0.f;
#pragma unroll
  for (int c = 0; c < 4; ++c) {
    // stage features [16c, 16c+16) for rows [row0, row0+256) -- coalesced
    // 64B-granule loads: lanes 4r..4r+3 cover one row's 64B chunk.
#pragma unroll
    for (int p = 0; p < 4; ++p) {
      const int row = p * 64 + (tid >> 2);
      const int q4 = (tid & 3) << 2;
      const float4 v = *reinterpret_cast<const float4*>(
          x + (row0 + (size_t)row) * 64 + c * 16 + q4);
      float* d = &xt[row * 17 + q4];
      d[0] = v.x; d[1] = v.y; d[2] = v.z; d[3] = v.w;
    }
    __syncthreads();
#pragma unroll
    for (int f = 0; f < 16; ++f) {
      const float xv = xt[tid * 17 + f];   // stride 17: conflict-free
      const int fg = c * 16 + f;
      a0 = fmaf(xv, Wp[fg], a0);           // W reads wave-uniform -> s_load
      a1 = fmaf(xv, Wp[64 + fg], a1);
      a2 = fmaf(xv, Wp[128 + fg], a2);
      a3 = fmaf(xv, Wp[192 + fg], a3);
    }
    __syncthreads();
  }

  const float t0 = tanhf(a0 + bp[0]);
  const float t1 = tanhf(a1 + bp[1]);
  const float t2 = tanhf(a2 + bp[2]);
  const float t3 = tanhf(a3 + bp[3]);

  float c0, s0, c1, s1, c2, s2, c3, s3;
  __sincosf(t0, &s0, &c0);
  __sincosf(t1, &s1, &c1);
  __sincosf(t2, &s2, &c2);
  __sincosf(t3, &s3, &c3);

  // g[p] = f0[i0]*f1[i1], h[q] = f2[i2]*f3[i3], f = (1, cos, sin)
  const float g[9] = {1.f, c1, s1, c0, c0 * c1, c0 * s1, s0, s0 * c1, s0 * s1};
  const float h[9] = {1.f, c3, s3, c2, c2 * c3, c2 * s3, s2, s2 * c3, s2 * s3};

  float e0 = 0.f, e1 = 0.f, e2 = 0.f, e3 = 0.f;
#pragma unroll
  for (int p = 0; p < 9; ++p) {
#pragma unroll
    for (int q = 0; q < 9; ++q) {
      const float t = g[p] * h[q];
      const float* a4 = &A[(p * 9 + q) * 4];   // uniform -> s_load
      e0 = fmaf(a4[0], t, e0);
      e1 = fmaf(a4[1], t, e1);
      e2 = fmaf(a4[2], t, e2);
      e3 = fmaf(a4[3], t, e3);
    }
  }
  reinterpret_cast<float4*>(out)[row0 + tid] = make_float4(e0, e1, e2, e3);
}

extern "C" void kernel_launch(void* const* d_in, const int* in_sizes, int n_in,
                              void* d_out, int out_size, void* d_ws, size_t ws_size,
                              hipStream_t stream) {
  const float* x  = (const float*)d_in[0];
  const float* Wp = (const float*)d_in[1];
  const float* bp = (const float*)d_in[2];
  const float* qw = (const float*)d_in[3];
  float* out = (float*)d_out;
  float* A = (float*)d_ws;   // 324 floats

  qprep_kernel<<<1, 256, 0, stream>>>(qw, A);

  const int B = in_sizes[0] / 64;        // 524288
  qmain_kernel<<<B / 256, 256, 0, stream>>>(x, Wp, bp, A, out);
}

// Round 4
// 41.695 us; speedup vs baseline: 3.7294x; 1.0215x over previous
//
#include <hip/hip_runtime.h>
#include <cmath>

// Single fused kernel.
//
// Math: angles = tanh(x@W^T + b); the fixed 3-layer circuit is a constant
// 16x16 unitary U. exps[w] = psi^T M_w psi with M_w = Re(U^dag Z_w U) and
// psi = prod_w (cos a_w/2, sin a_w/2). Since psi psi^T factorizes over wires
// as (I/2 + cos(a)Z/2 + sin(a)X/2), the whole tail collapses to a 81x4
// coefficient tensor A contracted with g[9] x h[9] per element.
//
// Every block computes A redundantly in LDS (~1-2us, hidden under the
// round-0 x loads issued BEFORE the prep), then streams 256 rows of x.
__global__ __launch_bounds__(256) void qfused_kernel(
    const float* __restrict__ x,    // [B][64]
    const float* __restrict__ Wp,   // [4][64]
    const float* __restrict__ bp,   // [4]
    const float* __restrict__ qw,   // [3][4][2]
    float* __restrict__ out)        // [B][4]
{
  // LDS union: prep scratch lives inside the xt region (used only after
  // prep's final barrier). A[] sits past xt and persists.
  __shared__ float lds[4352 + 324];   // 18.7 KB
  constexpr int SRE = 0;              // 16x17
  constexpr int SIM = 272;            // 16x17
  constexpr int MOF = 544;            // 4x16x16
  constexpr int AOF = 4352;           // 324
  float* xt = lds;                    // 256 rows x 16 feats, stride 17

  const int tid = threadIdx.x;
  const size_t row0 = (size_t)blockIdx.x * 256;

  // ---- issue round-0 x loads (in flight during prep) ----
  float4 rbuf[4];
  {
    const int rrow = tid >> 2, q4 = (tid & 3) << 2;
#pragma unroll
    for (int p = 0; p < 4; ++p)
      rbuf[p] = *reinterpret_cast<const float4*>(
          x + (row0 + (size_t)(p * 64 + rrow)) * 64 + 0 * 16 + q4);
  }

  // ---- prep: build A[81][4] (256 threads = 16 cols x 16 amplitudes) ----
  {
    const int col = tid >> 4;
    const int u   = tid & 15;
    lds[SRE + col * 17 + u] = (u == col) ? 1.0f : 0.0f;
    lds[SIM + col * 17 + u] = 0.0f;
    __syncthreads();

#pragma unroll
    for (int l = 0; l < 3; ++l) {
#pragma unroll
      for (int w = 0; w < 4; ++w) {
        const int mask = 8 >> w;     // wire 0 = MSB
        float sh, ch, sh2, ch2;
        __sincosf(0.5f * qw[(l * 4 + w) * 2 + 0], &sh, &ch);    // RY
        __sincosf(0.5f * qw[(l * 4 + w) * 2 + 1], &sh2, &ch2);  // RZ
        const int ua = u & ~mask, ub = u | mask;
        const float ar = lds[SRE + col * 17 + ua], ai = lds[SIM + col * 17 + ua];
        const float br = lds[SRE + col * 17 + ub], bi = lds[SIM + col * 17 + ub];
        __syncthreads();
        float nr, ni;
        if (u & mask) { nr = sh * ar + ch * br; ni = sh * ai + ch * bi; }
        else          { nr = ch * ar - sh * br; ni = ch * ai - sh * bi; }
        float rr, ri;
        if (u & mask) { rr = ch2 * nr - sh2 * ni; ri = ch2 * ni + sh2 * nr; }
        else          { rr = ch2 * nr + sh2 * ni; ri = ch2 * ni - sh2 * nr; }
        lds[SRE + col * 17 + u] = rr; lds[SIM + col * 17 + u] = ri;
        __syncthreads();
      }
      // CNOT ring (0,1)(1,2)(2,3)(3,0) as one permutation
      int src = u;
      if (src & 1) src ^= 8;
      if (src & 2) src ^= 1;
      if (src & 4) src ^= 2;
      if (src & 8) src ^= 4;
      const float pr = lds[SRE + col * 17 + src], pi = lds[SIM + col * 17 + src];
      __syncthreads();
      lds[SRE + col * 17 + u] = pr; lds[SIM + col * 17 + u] = pi;
      __syncthreads();
    }

    // M[w][s][t] = sum_u z_w(u) * Re(conj(U[u,s]) U[u,t]);  sre[col][u]=U[u][col]
#pragma unroll
    for (int k = 0; k < 4; ++k) {
      const int idx = tid + 256 * k;
      const int w = idx >> 8, s = (idx >> 4) & 15, t = idx & 15;
      const int mask = 8 >> w;
      float acc = 0.0f;
#pragma unroll
      for (int uu = 0; uu < 16; ++uu) {
        const float z = (uu & mask) ? -1.0f : 1.0f;
        acc += z * (lds[SRE + s * 17 + uu] * lds[SRE + t * 17 + uu] +
                    lds[SIM + s * 17 + uu] * lds[SIM + t * 17 + uu]);
      }
      lds[MOF + ((w * 16 + s) * 16 + t)] = acc;
    }
    __syncthreads();

    // A[pq][w]: 16-term sparse Pauli-basis contraction of M.
    // NOTE: strided loop (NOT `if (tid<324)`) -- threads 0..67 compute the
    // second slab 256..323; round-3 bug left those entries uninitialized.
    for (int idx = tid; idx < 324; idx += 256) {
      const int w = idx & 3, pq = idx >> 2;
      const int p = pq / 9, q = pq % 9;
      const int i0 = p / 3, i1 = p % 3, i2 = q / 3, i3 = q % 3;
      float acc = 0.0f;
#pragma unroll
      for (int comb = 0; comb < 16; ++comb) {
        int s = 0, t = 0;
        float coef = 0.0625f;
        int j;
        j = (comb >> 3) & 1; s |= j << 3; t |= ((i0 == 2) ? (j ^ 1) : j) << 3; if (i0 == 1 && j) coef = -coef;
        j = (comb >> 2) & 1; s |= j << 2; t |= ((i1 == 2) ? (j ^ 1) : j) << 2; if (i1 == 1 && j) coef = -coef;
        j = (comb >> 1) & 1; s |= j << 1; t |= ((i2 == 2) ? (j ^ 1) : j) << 1; if (i2 == 1 && j) coef = -coef;
        j = comb & 1;        s |= j;      t |= ((i3 == 2) ? (j ^ 1) : j);      if (i3 == 1 && j) coef = -coef;
        acc = fmaf(coef, lds[MOF + ((w * 16 + s) * 16 + t)], acc);
      }
      lds[AOF + idx] = acc;
    }
    __syncthreads();   // A ready; prep scratch region now dead
  }

  // ---- pipelined staging + GEMV: 4 rounds of 16 features ----
  const int rrow = tid >> 2, q4 = (tid & 3) << 2;
  float a0 = 0.f, a1 = 0.f, a2 = 0.f, a3 = 0.f;
#pragma unroll
  for (int c = 0; c < 4; ++c) {
    // write staged regs -> xt (coalesced writes, stride-17 rows)
#pragma unroll
    for (int p = 0; p < 4; ++p) {
      float* d = &xt[(p * 64 + rrow) * 17 + q4];
      d[0] = rbuf[p].x; d[1] = rbuf[p].y; d[2] = rbuf[p].z; d[3] = rbuf[p].w;
    }
    // issue next round's loads now -> latency hides under this round's GEMV
    if (c < 3) {
#pragma unroll
      for (int p = 0; p < 4; ++p)
        rbuf[p] = *reinterpret_cast<const float4*>(
            x + (row0 + (size_t)(p * 64 + rrow)) * 64 + (c + 1) * 16 + q4);
    }
    __syncthreads();
#pragma unroll
    for (int f = 0; f < 16; ++f) {
      const float xv = xt[tid * 17 + f];   // stride 17: conflict-free
      const int fg = c * 16 + f;
      a0 = fmaf(xv, Wp[fg], a0);           // uniform -> s_load
      a1 = fmaf(xv, Wp[64 + fg], a1);
      a2 = fmaf(xv, Wp[128 + fg], a2);
      a3 = fmaf(xv, Wp[192 + fg], a3);
    }
    if (c < 3) __syncthreads();
  }

  // ---- tail: tanh, sincos, 81-term contraction ----
  // tanh(a) = 1 - 2/(e^{2a}+1)  (error ~1e-7, threshold 2e-2)
  const float t0 = 1.0f - 2.0f / (__expf(2.0f * (a0 + bp[0])) + 1.0f);
  const float t1 = 1.0f - 2.0f / (__expf(2.0f * (a1 + bp[1])) + 1.0f);
  const float t2 = 1.0f - 2.0f / (__expf(2.0f * (a2 + bp[2])) + 1.0f);
  const float t3 = 1.0f - 2.0f / (__expf(2.0f * (a3 + bp[3])) + 1.0f);

  float c0, s0, c1, s1, c2, s2, c3, s3;
  __sincosf(t0, &s0, &c0);
  __sincosf(t1, &s1, &c1);
  __sincosf(t2, &s2, &c2);
  __sincosf(t3, &s3, &c3);

  const float g[9] = {1.f, c1, s1, c0, c0 * c1, c0 * s1, s0, s0 * c1, s0 * s1};
  const float h[9] = {1.f, c3, s3, c2, c2 * c3, c2 * s3, s2, s2 * c3, s2 * s3};

  float e0 = 0.f, e1 = 0.f, e2 = 0.f, e3 = 0.f;
#pragma unroll
  for (int p = 0; p < 9; ++p) {
#pragma unroll
    for (int q = 0; q < 9; ++q) {
      const float t = g[p] * h[q];
      const int base = AOF + (p * 9 + q) * 4;   // uniform -> LDS broadcast
      e0 = fmaf(lds[base + 0], t, e0);
      e1 = fmaf(lds[base + 1], t, e1);
      e2 = fmaf(lds[base + 2], t, e2);
      e3 = fmaf(lds[base + 3], t, e3);
    }
  }
  reinterpret_cast<float4*>(out)[row0 + tid] = make_float4(e0, e1, e2, e3);
}

extern "C" void kernel_launch(void* const* d_in, const int* in_sizes, int n_in,
                              void* d_out, int out_size, void* d_ws, size_t ws_size,
                              hipStream_t stream) {
  const float* x  = (const float*)d_in[0];
  const float* Wp = (const float*)d_in[1];
  const float* bp = (const float*)d_in[2];
  const float* qw = (const float*)d_in[3];
  float* out = (float*)d_out;

  const int B = in_sizes[0] / 64;   // 524288
  qfused_kernel<<<B / 256, 256, 0, stream>>>(x, Wp, bp, qw, out);
}